// Round 11
// baseline (332.321 us; speedup 1.0000x reference)
//
#include <hip/hip_runtime.h>
#include <cstddef>

// AttentiveFP forward. B=256 L=128 K=6 FA=39 FB=10 D=128 R=3 T=2. fp32 I/O.
// R11 = R10 with ONE change: k_round GRU kd-split to cut peak register
// pressure (48 f4 accumulators -> 32 then 8). Targets the residual ~23MB/round
// of unexplained HBM writes (suspected scratch spills near the (512,4)=128reg
// cap; reported VGPR=64 is arch-only). Pass A computes r,z gates (kd 0,1),
// collapses to 16 scalars; pass B computes kd=2. Weight frags are per-kd so
// NONE are re-loaded; only LDS A-frags re-read. Identical MFMA sequence per
// accumulator -> bit-identical results. Barrier count unchanged.
// Lesson from R8/R10: top-5 dispatch durations are worst-case instances;
// R8's "82us k_round" was an artifact (bench totals equal).

#define B_ 256
#define L_ 128
#define K_ 6
#define FA_ 39
#define FB_ 10
#define D_ 128
#define PAD_ 127
#define NEGC (-9.0e8f)
#define NA 32
#define NPAIR (NA * K_)   // 192

typedef unsigned short u16;
typedef unsigned int u32;
using s8 = __attribute__((ext_vector_type(8))) short;   // 8 x bf16
using f4 = __attribute__((ext_vector_type(4))) float;   // MFMA acc

#define WIH_H 0
#define WIH_L 49152
#define WHH_H 98304
#define WHH_L 147456
#define TW_H  196608
#define TW_L  212992
#define RND_BLK2 229376
#define NB16 (3 * RND_BLK2)
#define NMOLF (2 * 128 * 384)
#define PRE_BLKS 2048

__device__ __forceinline__ float lrelu(float x) { return x > 0.f ? x : 0.01f * x; }
__device__ __forceinline__ float eluf(float x)  { return x > 0.f ? x : expm1f(x); }
__device__ __forceinline__ float sigm(float x)  { return 1.f / (1.f + expf(-x)); }
__device__ __forceinline__ float b2f(u16 u) {
  union { u32 i; float f; } v; v.i = ((u32)u) << 16; return v.f;
}
__device__ __forceinline__ short f2b(float f) {  // RNE
  union { float f; u32 i; } v; v.f = f;
  u32 x = v.i;
  return (short)(u16)((x + 0x7FFFu + ((x >> 16) & 1u)) >> 16);
}

// Fused prep: blocks [0,PRE_BLKS) = per-atom precompute (h0/AP/P0);
// blocks [PRE_BLKS,..) = weight transform (frag-swizzled split bf16 + molT).
__global__ __launch_bounds__(256) void k_prep(
    // pre args
    const float* __restrict__ atom_list,
    const float* __restrict__ afc_w, const float* __restrict__ afc_b,
    const float* __restrict__ nbr_w,
    const float* __restrict__ aw0,
    u16* __restrict__ h0out, short* __restrict__ APg, float* __restrict__ PgA,
    // tr args
    const float* __restrict__ gwih, const float* __restrict__ gwhh,
    const float* __restrict__ attw,
    const float* __restrict__ mwih, const float* __restrict__ mwhh,
    short* __restrict__ wB, float* __restrict__ molT)
{
  int tid = threadIdx.x;
  if (blockIdx.x >= PRE_BLKS) {
    int idx = (blockIdx.x - PRE_BLKS) * 256 + tid;
    if (idx < NB16) {
      int r = idx / RND_BLK2, o = idx % RND_BLK2;
      float v; int lo;
      int e, kind;          // kind 0=wih, 1=whh, 2=tw
      if (o < 98304)      { kind = 0; lo = o / 49152; e = o % 49152; }
      else if (o < 196608){ kind = 1; int o2 = o - 98304; lo = o2 / 49152; e = o2 % 49152; }
      else                { kind = 2; int o2 = o - 196608; lo = o2 / 16384; e = o2 % 16384; }
      int gt = e >> 11, rem = e & 2047;
      int kc = rem >> 9, rem2 = rem & 511;
      int lane = rem2 >> 3, j = rem2 & 7;
      int col = lane & 15, quad = lane >> 4;
      int g = gt * 16 + col;
      int k = kc * 32 + quad * 8 + j;
      if (kind == 0)      v = gwih[(size_t)r * 49152 + g * 128 + k];
      else if (kind == 1) v = gwhh[(size_t)r * 49152 + g * 128 + k];
      else                v = attw[(size_t)r * 16384 + k * 128 + g];
      short hi = f2b(v);
      wB[idx] = lo ? f2b(v - b2f((u16)hi)) : hi;
    } else if (idx < NB16 + NMOLF) {
      int e2 = idx - NB16;
      int m = e2 / 49152, e = e2 % 49152, j = e / 384, g = e % 384;
      molT[e2] = (m ? mwhh : mwih)[g * 128 + j];
    }
    return;
  }

  // ---- pre branch (identical math to R3's k_pre; 256 thr, tid<128 active) ----
  int a0 = blockIdx.x * 16;
  __shared__ float xa[16 * 40];
  __shared__ float h0S[16][132];
  __shared__ float awS[128];
  __shared__ float partials[128];

  for (int i = tid; i < 16 * FA_; i += 256) {
    int a = i / FA_, c = i % FA_;
    xa[a * 40 + c] = atom_list[((size_t)(a0 + a)) * FA_ + c];
  }
  if (tid < 128) awS[tid] = aw0[tid];
  __syncthreads();

  if (tid < 128) {
    {
      float acc[16];
      float bv = afc_b[tid];
#pragma unroll
      for (int a = 0; a < 16; a++) acc[a] = bv;
#pragma unroll 2
      for (int j = 0; j < FA_; j++) {
        float w = afc_w[j * D_ + tid];
#pragma unroll
        for (int a = 0; a < 16; a++) acc[a] += xa[a * 40 + j] * w;
      }
#pragma unroll
      for (int a = 0; a < 16; a++) {
        float hv = lrelu(acc[a]);
        h0out[(size_t)(a0 + a) * D_ + tid] = (u16)f2b(hv);
        h0S[a][tid] = hv;
      }
    }
    {
      float acc[16];
#pragma unroll
      for (int a = 0; a < 16; a++) acc[a] = 0.f;
#pragma unroll 2
      for (int j = 0; j < FA_; j++) {
        float w = nbr_w[j * D_ + tid];
#pragma unroll
        for (int a = 0; a < 16; a++) acc[a] += xa[a * 40 + j] * w;
      }
#pragma unroll
      for (int a = 0; a < 16; a++)
        APg[(size_t)(a0 + a) * D_ + tid] = f2b(acc[a]);
    }
  }
  __syncthreads();
  if (tid < 128) {
    int a = tid >> 3, seg = tid & 7;
    float s = 0.f;
#pragma unroll
    for (int j = 0; j < 16; j++) s += h0S[a][seg * 16 + j] * awS[seg * 16 + j];
    partials[tid] = s;
  }
  __syncthreads();
  if (tid < 16) {
    float s = 0.f;
#pragma unroll
    for (int g = 0; g < 8; g++) s += partials[tid * 8 + g];
    PgA[a0 + tid] = s;
  }
}

// Per-pair Q0 = sum_d lrelu(AP[aidx]+bond[bidx]@Wb+nb) * awhi0.
__global__ __launch_bounds__(256) void k_q0(
    const float* __restrict__ bond_list,
    const float* __restrict__ nbr_w, const float* __restrict__ nbr_b,
    const float* __restrict__ aw0,
    const int* __restrict__ adeg, const int* __restrict__ bdeg,
    const short* __restrict__ APg, float* __restrict__ Q0g)
{
  int tid = threadIdx.x;
  __shared__ float WbS[10 * 128];
  __shared__ float nbS[128], ahS[128];
  for (int i = tid; i < 10 * 128; i += 256)
    WbS[i] = nbr_w[(FA_ + i / 128) * D_ + (i % 128)];
  if (tid < 128) { nbS[tid] = nbr_b[tid]; ahS[tid] = aw0[D_ + tid]; }
  __syncthreads();

  int p = blockIdx.x * 64 + (tid >> 2);
  int seg = tid & 3;
  int aidx = adeg[p], bidx = bdeg[p];
  int bb = p / (L_ * K_);
  const short* rowA = APg + ((size_t)bb * L_ + aidx) * D_;
  const float* brow = bond_list + ((size_t)bb * L_ + bidx) * FB_;
  float bnd[10];
#pragma unroll
  for (int m = 0; m < 10; m++) bnd[m] = brow[m];
  float s = 0.f;
  int j0 = seg * 32;
#pragma unroll 4
  for (int j = j0; j < j0 + 32; j++) {
    float v = b2f((u16)rowA[j]) + nbS[j];
#pragma unroll
    for (int m = 0; m < 10; m++) v += bnd[m] * WbS[m * 128 + j];
    s += lrelu(v) * ahS[j];
  }
  s += __shfl_xor(s, 1, 64);
  s += __shfl_xor(s, 2, 64);
  if (seg == 0) Q0g[p] = s;
}

template <int FIRST>
__global__ __launch_bounds__(512, 4) void k_round(
    const u16* __restrict__ hin,     // bf16 h
    u16* __restrict__ hout,          // bf16 h
    const float* __restrict__ bond_list,
    const int* __restrict__ adeg, const int* __restrict__ bdeg,
    const float* __restrict__ nbr_w, const float* __restrict__ nbr_b,
    const short* __restrict__ APg,
    const float* __restrict__ ab,
    const float* __restrict__ awN,
    const float* __restrict__ tb,
    const short* __restrict__ wR,
    const float* __restrict__ bih, const float* __restrict__ bhh,
    const float* __restrict__ Pr, const float* __restrict__ Qr,
    float* __restrict__ Pw, float* __restrict__ Qw)
{
  int tid  = threadIdx.x;
  int lane = tid & 63;
  int wv   = tid >> 6;         // wave 0..7
  int quad = lane >> 4;
  int col  = lane & 15;
  int aT   = tid >> 4;         // atom 0..31 (staging/ybar/copy mapping)
  int dg   = (tid & 15) * 8;   // dim-group base 0,8,..,120
  // XCD-bijective swizzle (grid=1024, 8 XCDs): the 4 tiles of each molecule
  // land on ONE XCD, and the mapping is launch-stable so round r+1 reads h
  // from the same L2 that round r wrote.
  int tile = (blockIdx.x & 7) * 128 + (blockIdx.x >> 3);
  int a0   = tile * NA;
  int bb   = a0 >> 7;

  const short* wihH = wR + WIH_H;
  const short* wihL = wR + WIH_L;
  const short* whhH = wR + WHH_H;
  const short* whhL = wR + WHH_L;
  const short* twH  = wR + TW_H;
  const short* twL  = wR + TW_L;

  __shared__ short hrowH[NA][136];                 // exact bf16 h (reused for hn out)
  __shared__ __align__(16) char arena[17408];      // ybar/ctx | hnrelu
  __shared__ float awNS[256];
  __shared__ float partials[512];
  __shared__ float pS[NA], qS[NPAIR], wkS[NPAIR], wsS[NA];
  __shared__ int aidxS[NPAIR];
  __shared__ int bidxS[FIRST ? NPAIR : 1];
  __shared__ float bwS[FIRST ? 1920 : 1];          // bond[192][10] only

  short* ybarH = (short*)arena;               // [32][136] (ctx reuses)
  short* ybarL = (short*)(arena + 8704);
  float* hnrel = (float*)arena;               // epilogue relu(hn) [32][132]

  if (tid < NPAIR) {
    int av = adeg[a0 * K_ + tid];
    aidxS[tid] = av;
    if (FIRST) { bidxS[tid] = bdeg[a0 * K_ + tid]; qS[tid] = Qr[a0 * K_ + tid]; }
    else       qS[tid] = Qr[bb * L_ + av];
  } else if (tid < NPAIR + NA) {
    pS[tid - NPAIR] = Pr[a0 + (tid - NPAIR)];
  }
  if (tid < 256) awNS[tid] = awN[tid];
  __syncthreads();

  // ---------- Phase 1: h tile (16B/thread) + FIRST bond staging + softmax ----------
  if (FIRST) {
    for (int i = tid; i < NPAIR * 10; i += 512) {
      int p = i / 10, m = i % 10;
      bwS[p * 10 + m] = bond_list[((size_t)bb * L_ + bidxS[p]) * FB_ + m];
    }
  }
  *(s8*)&hrowH[aT][dg] = *(const s8*)&hin[(size_t)(a0 + aT) * D_ + dg];

  // Softmax over K (first 32 lanes; fused into this barrier interval)
  if (tid < NA) {
    int a = tid;
    float abv = ab[0];
    float sc[K_];
    float m = -3.0e38f;
#pragma unroll
    for (int k = 0; k < K_; k++) {
      float s = lrelu(pS[a] + qS[a * K_ + k] + abv);
      if (aidxS[a * K_ + k] == PAD_) s += NEGC;
      sc[k] = s; m = fmaxf(m, s);
    }
    float es = 0.f;
#pragma unroll
    for (int k = 0; k < K_; k++) { sc[k] = expf(sc[k] - m); es += sc[k]; }
    float ws = 0.f;
#pragma unroll
    for (int k = 0; k < K_; k++) {
      float w = (aidxS[a * K_ + k] == PAD_) ? 0.f : sc[k] / es;
      wkS[a * K_ + k] = w; ws += w;
    }
    wsS[a] = ws;
  }
  __syncthreads();

  // ---------- ybar hi/lo: thread = (atom aT, dims dg..dg+7), 16B gathers ----------
  {
    float yb[8];
#pragma unroll
    for (int j = 0; j < 8; j++) yb[j] = 0.f;
    if (FIRST) {
#pragma unroll
      for (int h = 0; h < 2; h++) {
        float Wr[10][4];
#pragma unroll
        for (int m = 0; m < 10; m++) {
          float4 w = *(const float4*)&nbr_w[(FA_ + m) * D_ + dg + h * 4];
          Wr[m][0] = w.x; Wr[m][1] = w.y; Wr[m][2] = w.z; Wr[m][3] = w.w;
        }
        float4 nb4 = *(const float4*)&nbr_b[dg + h * 4];
        float nb[4] = {nb4.x, nb4.y, nb4.z, nb4.w};
#pragma unroll
        for (int k = 0; k < K_; k++) {
          int p = aT * K_ + k;
          ushort4 ap4 = *(const ushort4*)&APg[((size_t)bb * L_ + aidxS[p]) * D_ + dg + h * 4];
          float nf[4] = { b2f(ap4.x) + nb[0], b2f(ap4.y) + nb[1],
                          b2f(ap4.z) + nb[2], b2f(ap4.w) + nb[3] };
#pragma unroll
          for (int m = 0; m < 10; m++) {
            float bv = bwS[p * 10 + m];
#pragma unroll
            for (int j = 0; j < 4; j++) nf[j] += bv * Wr[m][j];
          }
          float w = wkS[p];
#pragma unroll
          for (int j = 0; j < 4; j++) yb[h * 4 + j] += w * lrelu(nf[j]);
        }
      }
    } else {
#pragma unroll
      for (int k = 0; k < K_; k++) {
        int p = aT * K_ + k;
        float w = wkS[p];
        s8 hv8 = *(const s8*)&hin[((size_t)bb * L_ + aidxS[p]) * D_ + dg];
#pragma unroll
        for (int j = 0; j < 8; j++) yb[j] += w * fmaxf(b2f((u16)hv8[j]), 0.f);
      }
    }
    s8 yh8, yl8;
#pragma unroll
    for (int j = 0; j < 8; j++) {
      short hi = f2b(yb[j]);
      yh8[j] = hi;
      yl8[j] = f2b(yb[j] - b2f((u16)hi));
    }
    *(s8*)&ybarH[aT * 136 + dg] = yh8;
    *(s8*)&ybarL[aT * 136 + dg] = yl8;
  }
  __syncthreads();

  // ---------- ctx = elu(ybar @ twT^T + wsum*tb), split MFMA (swizzled B) ----------
  {
    f4 c2[2] = {};
#pragma unroll
    for (int k0c = 0; k0c < 4; k0c++) {
      int fo = ((wv * 4 + k0c) * 64 + lane) * 8;
      s8 bwh = *(const s8*)&twH[fo];
      s8 bwl = *(const s8*)&twL[fo];
#pragma unroll
      for (int at = 0; at < 2; at++) {
        s8 ayh = *(const s8*)&ybarH[(at * 16 + col) * 136 + k0c * 32 + quad * 8];
        s8 ayl = *(const s8*)&ybarL[(at * 16 + col) * 136 + k0c * 32 + quad * 8];
        c2[at] = __builtin_amdgcn_mfma_f32_16x16x32_bf16(ayh, bwh, c2[at], 0, 0, 0);
        c2[at] = __builtin_amdgcn_mfma_f32_16x16x32_bf16(ayl, bwh, c2[at], 0, 0, 0);
        c2[at] = __builtin_amdgcn_mfma_f32_16x16x32_bf16(ayh, bwl, c2[at], 0, 0, 0);
      }
    }
    __syncthreads();
    int g = wv * 16 + col;
    float tbv = tb[g];
#pragma unroll
    for (int at = 0; at < 2; at++) {
#pragma unroll
      for (int r = 0; r < 4; r++) {
        int a = at * 16 + quad * 4 + r;
        float c = eluf(c2[at][r] + wsS[a] * tbv);
        short chs = f2b(c);
        ybarH[a * 136 + g] = chs;                    // ctxH
        ybarL[a * 136 + g] = f2b(c - b2f((u16)chs)); // ctxL
      }
    }
  }
  __syncthreads();

  // ---------- GRU via split MFMA, kd-split (A: r/z gates, B: n gate) ----------
  // Same MFMA sequence per accumulator as the fused version -> identical FP.
  {
    const short* ctxH = ybarH;
    const short* ctxL = ybarL;
    int ic = wv * 16 + col;
    float r8[8], z8[8];

    // ---- pass A: kd = 0,1 (reset/update gates), 16 f4 accumulators ----
    {
      f4 gi[2][2] = {}, gh[2][2] = {};
#pragma unroll
      for (int k0c = 0; k0c < 4; k0c++) {
        s8 ach[2], acl[2], ahh[2];
#pragma unroll
        for (int at = 0; at < 2; at++) {
          ach[at] = *(const s8*)&ctxH[(at * 16 + col) * 136 + k0c * 32 + quad * 8];
          acl[at] = *(const s8*)&ctxL[(at * 16 + col) * 136 + k0c * 32 + quad * 8];
          ahh[at] = *(const s8*)&hrowH[at * 16 + col][k0c * 32 + quad * 8];
        }
#pragma unroll
        for (int kd = 0; kd < 2; kd++) {
          int gt = wv + kd * 8;
          int fo = ((gt * 4 + k0c) * 64 + lane) * 8;
          s8 bi_h = *(const s8*)&wihH[fo];
          s8 bi_l = *(const s8*)&wihL[fo];
          s8 bh_h = *(const s8*)&whhH[fo];
          s8 bh_l = *(const s8*)&whhL[fo];
#pragma unroll
          for (int at = 0; at < 2; at++) {
            gi[at][kd] = __builtin_amdgcn_mfma_f32_16x16x32_bf16(ach[at], bi_h, gi[at][kd], 0, 0, 0);
            gi[at][kd] = __builtin_amdgcn_mfma_f32_16x16x32_bf16(acl[at], bi_h, gi[at][kd], 0, 0, 0);
            gi[at][kd] = __builtin_amdgcn_mfma_f32_16x16x32_bf16(ach[at], bi_l, gi[at][kd], 0, 0, 0);
            gh[at][kd] = __builtin_amdgcn_mfma_f32_16x16x32_bf16(ahh[at], bh_h, gh[at][kd], 0, 0, 0);
            gh[at][kd] = __builtin_amdgcn_mfma_f32_16x16x32_bf16(ahh[at], bh_l, gh[at][kd], 0, 0, 0);
          }
        }
      }
      float bi0 = bih[ic], bi1 = bih[D_ + ic];
      float bh0 = bhh[ic], bh1 = bhh[D_ + ic];
#pragma unroll
      for (int at = 0; at < 2; at++)
#pragma unroll
        for (int r = 0; r < 4; r++) {
          r8[at * 4 + r] = sigm(gi[at][0][r] + bi0 + gh[at][0][r] + bh0);
          z8[at * 4 + r] = sigm(gi[at][1][r] + bi1 + gh[at][1][r] + bh1);
        }
    }

    // ---- pass B: kd = 2 (candidate gate), 4 f4 accumulators ----
    {
      f4 gi2[2] = {}, gh2[2] = {};
#pragma unroll
      for (int k0c = 0; k0c < 4; k0c++) {
        s8 ach[2], acl[2], ahh[2];
#pragma unroll
        for (int at = 0; at < 2; at++) {
          ach[at] = *(const s8*)&ctxH[(at * 16 + col) * 136 + k0c * 32 + quad * 8];
          acl[at] = *(const s8*)&ctxL[(at * 16 + col) * 136 + k0c * 32 + quad * 8];
          ahh[at] = *(const s8*)&hrowH[at * 16 + col][k0c * 32 + quad * 8];
        }
        int gt = wv + 16;
        int fo = ((gt * 4 + k0c) * 64 + lane) * 8;
        s8 bi_h = *(const s8*)&wihH[fo];
        s8 bi_l = *(const s8*)&wihL[fo];
        s8 bh_h = *(const s8*)&whhH[fo];
        s8 bh_l = *(const s8*)&whhL[fo];
#pragma unroll
        for (int at = 0; at < 2; at++) {
          gi2[at] = __builtin_amdgcn_mfma_f32_16x16x32_bf16(ach[at], bi_h, gi2[at], 0, 0, 0);
          gi2[at] = __builtin_amdgcn_mfma_f32_16x16x32_bf16(acl[at], bi_h, gi2[at], 0, 0, 0);
          gi2[at] = __builtin_amdgcn_mfma_f32_16x16x32_bf16(ach[at], bi_l, gi2[at], 0, 0, 0);
          gh2[at] = __builtin_amdgcn_mfma_f32_16x16x32_bf16(ahh[at], bh_h, gh2[at], 0, 0, 0);
          gh2[at] = __builtin_amdgcn_mfma_f32_16x16x32_bf16(ahh[at], bh_l, gh2[at], 0, 0, 0);
        }
      }
      __syncthreads();   // all waves done reading hrowH/yb before in-place write

      float bi2 = bih[2 * D_ + ic];
      float bh2 = bhh[2 * D_ + ic];
#pragma unroll
      for (int at = 0; at < 2; at++) {
#pragma unroll
        for (int r = 0; r < 4; r++) {
          int a = at * 16 + quad * 4 + r;
          float rr = r8[at * 4 + r];
          float zz = z8[at * 4 + r];
          float nn = tanhf(gi2[at][r] + bi2 + rr * (gh2[at][r] + bh2));
          float hv = b2f((u16)hrowH[a][ic]);
          float hn = (1.f - zz) * nn + zz * hv;
          hrowH[a][ic] = f2b(hn);                    // stage bf16 hn in place
          if (Pw) hnrel[a * 132 + ic] = fmaxf(hn, 0.f);
        }
      }
    }
  }
  __syncthreads();

  // ---------- Coalesced hout copy (16B/thread, full 8KB tile) ----------
  *(s8*)&hout[(size_t)(a0 + aT) * D_ + dg] = *(const s8*)&hrowH[aT][dg];

  // ---------- Epilogue: P/Q for next round (skipped on last round) ----------
  if (Pw) {
    {
      int a = tid >> 4, dt = (tid >> 3) & 1, seg = tid & 7;
      float s = 0.f;
#pragma unroll
      for (int j = 0; j < 16; j++)
        s += hnrel[a * 132 + seg * 16 + j] * awNS[dt * 128 + seg * 16 + j];
      partials[tid] = s;
    }
    __syncthreads();
    if (tid < 64) {
      int a = tid >> 1, dt = tid & 1;
      float s = 0.f;
#pragma unroll
      for (int seg = 0; seg < 8; seg++) s += partials[a * 16 + dt * 8 + seg];
      if (dt) Qw[a0 + a] = s; else Pw[a0 + a] = s;
    }
  }
}

// --- block-wide reductions over 128 values (waves 0-1 hold data) ---
__device__ __forceinline__ float blk_sum128(float v, int tid, float* redS) {
  if (tid < 128) {
#pragma unroll
    for (int s = 1; s < 64; s <<= 1) v += __shfl_xor(v, s, 64);
    if ((tid & 63) == 0) redS[tid >> 6] = v;
  }
  __syncthreads();
  float r = redS[0] + redS[1];
  __syncthreads();
  return r;
}
__device__ __forceinline__ float blk_max128(float v, int tid, float* redS) {
  if (tid < 128) {
#pragma unroll
    for (int s = 1; s < 64; s <<= 1) v = fmaxf(v, __shfl_xor(v, s, 64));
    if ((tid & 63) == 0) redS[tid >> 6] = v;
  }
  __syncthreads();
  float r = fmaxf(redS[0], redS[1]);
  __syncthreads();
  return r;
}

__global__ __launch_bounds__(512) void k_mol(
    const u16* __restrict__ hfin,    // bf16 final h
    float* __restrict__ hcopy,       // d_out h region (fp32)
    const float* __restrict__ amask,
    const float* __restrict__ maw, const float* __restrict__ mab,
    const float* __restrict__ mtw, const float* __restrict__ mtb,
    const float* __restrict__ wih_t, const float* __restrict__ whh_t,
    const float* __restrict__ bih, const float* __restrict__ bhh,
    const float* __restrict__ ow, const float* __restrict__ ob,
    float* __restrict__ pred)
{
  int b = blockIdx.x;
  int tid = threadIdx.x;
  int t128 = tid & 127;
  int qf = tid >> 7;           // quarter 0..3
  __shared__ float actS[L_][D_ + 1];
  __shared__ float redS[2];
  __shared__ float par4[4][132];
  __shared__ float pg[3][6][132];
  __shared__ float wgt[128], ybv[132], ctx[132], mfS[132], amol[132];
  __shared__ float msk[128], mawh[128], scf[128];

  if (qf == 0) { msk[t128] = amask[b * L_ + t128]; mawh[t128] = maw[D_ + t128]; }
  for (int i = 0; i < 32; i++) {
    int l = qf * 32 + i;
    float hv = b2f(hfin[(size_t)(b * L_ + l) * D_ + t128]);
    hcopy[(size_t)(b * L_ + l) * D_ + t128] = hv;
    actS[l][t128] = fmaxf(hv, 0.f);
  }
  __syncthreads();

  // mol_feature (l-split quarters)
  {
    float s = 0.f;
    for (int i = 0; i < 32; i++) { int l = qf * 32 + i; s += actS[l][t128] * msk[l]; }
    par4[qf][t128] = s;
  }
  __syncthreads();
  if (qf == 0) {
    float mf = par4[0][t128] + par4[1][t128] + par4[2][t128] + par4[3][t128];
    mfS[t128] = mf; amol[t128] = fmaxf(mf, 0.f);
  }
  __syncthreads();

  float mabv = mab[0];

  for (int t = 0; t < 2; t++) {
    // s0
    float s0 = blk_sum128((tid < 128) ? amol[tid] * maw[tid] : 0.f, tid, redS);

    // sc[l=t128] (j-split quarters)
    {
      float s = 0.f;
      for (int i = 0; i < 32; i++) { int j = qf * 32 + i; s += actS[t128][j] * mawh[j]; }
      par4[qf][t128] = s;
    }
    __syncthreads();
    if (qf == 0) {
      float sc = lrelu(s0 + mabv + par4[0][t128] + par4[1][t128] + par4[2][t128] + par4[3][t128]);
      if (msk[t128] == 0.f) sc += NEGC;
      scf[t128] = sc;
    }
    __syncthreads();

    // softmax over l
    float scv = scf[t128];
    float mx = blk_max128((tid < 128) ? scv : -3.0e38f, tid, redS);
    float e = expf(scv - mx);
    float es = blk_sum128((tid < 128) ? e : 0.f, tid, redS);
    float w = (e / es) * msk[t128];
    if (qf == 0) wgt[t128] = w;
    float wsum = blk_sum128((tid < 128) ? w : 0.f, tid, redS);

    // y[j=t128] (l-split quarters)
    {
      float s = 0.f;
      for (int i = 0; i < 32; i++) { int l = qf * 32 + i; s += wgt[l] * actS[l][t128]; }
      par4[qf][t128] = s;
    }
    __syncthreads();
    if (qf == 0) ybv[t128] = par4[0][t128] + par4[1][t128] + par4[2][t128] + par4[3][t128];
    __syncthreads();

    // ctx[g=t128] (j-split quarters)
    {
      float s = 0.f;
#pragma unroll 2
      for (int i = 0; i < 32; i++) { int j = qf * 32 + i; s += ybv[j] * mtw[j * D_ + t128]; }
      par4[qf][t128] = s;
    }
    __syncthreads();
    if (qf == 0)
      ctx[t128] = eluf(par4[0][t128] + par4[1][t128] + par4[2][t128] + par4[3][t128]
                       + wsum * mtb[t128]);
    __syncthreads();

    // GRU (j-split quarters, x-stationary)
    {
      float gi0 = 0, gi1 = 0, gi2 = 0, gh0 = 0, gh1 = 0, gh2 = 0;
#pragma unroll 2
      for (int i = 0; i < 32; i++) {
        int j = qf * 32 + i;
        const float* wi = wih_t + (size_t)j * 384;
        const float* wh = whh_t + (size_t)j * 384;
        float xc = ctx[j], xh = mfS[j];
        gi0 += xc * wi[t128]; gi1 += xc * wi[128 + t128]; gi2 += xc * wi[256 + t128];
        gh0 += xh * wh[t128]; gh1 += xh * wh[128 + t128]; gh2 += xh * wh[256 + t128];
      }
      if (qf > 0) {
        pg[qf - 1][0][t128] = gi0; pg[qf - 1][1][t128] = gi1; pg[qf - 1][2][t128] = gi2;
        pg[qf - 1][3][t128] = gh0; pg[qf - 1][4][t128] = gh1; pg[qf - 1][5][t128] = gh2;
      }
      __syncthreads();
      if (qf == 0) {
        gi0 += pg[0][0][t128] + pg[1][0][t128] + pg[2][0][t128] + bih[t128];
        gi1 += pg[0][1][t128] + pg[1][1][t128] + pg[2][1][t128] + bih[128 + t128];
        gi2 += pg[0][2][t128] + pg[1][2][t128] + pg[2][2][t128] + bih[256 + t128];
        gh0 += pg[0][3][t128] + pg[1][3][t128] + pg[2][3][t128] + bhh[t128];
        gh1 += pg[0][4][t128] + pg[1][4][t128] + pg[2][4][t128] + bhh[128 + t128];
        gh2 += pg[0][5][t128] + pg[1][5][t128] + pg[2][5][t128] + bhh[256 + t128];
        float r = sigm(gi0 + gh0);
        float z = sigm(gi1 + gh1);
        float n = tanhf(gi2 + r * gh2);
        float hn = (1.f - z) * n + z * mfS[t128];
        mfS[t128] = hn;
        amol[t128] = fmaxf(hn, 0.f);
      }
      __syncthreads();
    }
  }

  float fin = blk_sum128((tid < 128) ? mfS[tid] * ow[tid] : 0.f, tid, redS);
  if (tid == 0) pred[b] = fin + ob[0];
}

extern "C" void kernel_launch(void* const* d_in, const int* in_sizes, int n_in,
                              void* d_out, int out_size, void* d_ws, size_t ws_size,
                              hipStream_t stream) {
  const float* atom_list    = (const float*)d_in[0];
  const float* bond_list    = (const float*)d_in[1];
  const float* atom_mask    = (const float*)d_in[2];
  const float* atom_fc_w    = (const float*)d_in[3];
  const float* atom_fc_b    = (const float*)d_in[4];
  const float* nbr_fc_w     = (const float*)d_in[5];
  const float* nbr_fc_b     = (const float*)d_in[6];
  const float* align_w      = (const float*)d_in[7];
  const float* align_b      = (const float*)d_in[8];
  const float* attend_w     = (const float*)d_in[9];
  const float* attend_b     = (const float*)d_in[10];
  const float* gru_wih      = (const float*)d_in[11];
  const float* gru_whh      = (const float*)d_in[12];
  const float* gru_bih      = (const float*)d_in[13];
  const float* gru_bhh      = (const float*)d_in[14];
  const float* mol_align_w  = (const float*)d_in[15];
  const float* mol_align_b  = (const float*)d_in[16];
  const float* mol_attend_w = (const float*)d_in[17];
  const float* mol_attend_b = (const float*)d_in[18];
  const float* mol_gru_wih  = (const float*)d_in[19];
  const float* mol_gru_whh  = (const float*)d_in[20];
  const float* mol_gru_bih  = (const float*)d_in[21];
  const float* mol_gru_bhh  = (const float*)d_in[22];
  const float* out_w        = (const float*)d_in[23];
  const float* out_b        = (const float*)d_in[24];
  const int*   adeg         = (const int*)d_in[25];
  const int*   bdeg         = (const int*)d_in[26];

  const size_t NH = (size_t)B_ * L_ * D_;
  u16*   hA   = (u16*)d_ws;              // NH shorts = 8.39 MB
  u16*   hB   = hA + NH;                 // NH shorts = 8.39 MB
  short* wB   = (short*)(hB + NH);       // NB16 shorts = 1.38 MB
  float* molT = (float*)(wB + NB16);     // NMOLF floats = 0.39 MB
  float* PgA  = molT + NMOLF;            // 4 x 128KB P/Q buffers
  float* QgA  = PgA + B_ * L_;
  float* PgB  = QgA + B_ * L_;
  float* QgB  = PgB + B_ * L_;
  short* APg  = (short*)(QgB + B_ * L_); // NH shorts = 8.39 MB
  float* Q0g  = (float*)(APg + NH);      // B*L*K floats = 0.79 MB
  float* hOut = (float*)d_out;
  float* pred = hOut + NH;

  // fused prep: 2048 pre-blocks + 3072 tr-blocks (concurrent)
  k_prep<<<dim3(PRE_BLKS + (NB16 + NMOLF) / 256), dim3(256), 0, stream>>>(
      atom_list, atom_fc_w, atom_fc_b, nbr_fc_w, align_w, hA, APg, PgA,
      gru_wih, gru_whh, attend_w, mol_gru_wih, mol_gru_whh, wB, molT);

  k_q0<<<dim3(B_ * L_ * K_ / 64), dim3(256), 0, stream>>>(
      bond_list, nbr_fc_w, nbr_fc_b, align_w, adeg, bdeg, APg, Q0g);

  dim3 blk(512), grd(B_ * L_ / NA);

  // r0: hA -> hB ; r1: hB -> hA ; r2: hA -> hB ; k_mol: hB -> d_out
  k_round<1><<<grd, blk, 0, stream>>>(
      hA, hB, bond_list, adeg, bdeg, nbr_fc_w, nbr_fc_b, APg,
      align_b, align_w + 2 * D_, attend_b,
      wB + 0 * (size_t)RND_BLK2, gru_bih, gru_bhh,
      PgA, Q0g, PgB, QgB);
  k_round<0><<<grd, blk, 0, stream>>>(
      hB, hA, bond_list, adeg, bdeg, nbr_fc_w, nbr_fc_b, APg,
      align_b + 1, align_w + 4 * D_, attend_b + D_,
      wB + 1 * (size_t)RND_BLK2, gru_bih + 3 * D_, gru_bhh + 3 * D_,
      PgB, QgB, PgA, QgA);
  k_round<0><<<grd, blk, 0, stream>>>(
      hA, hB, bond_list, adeg, bdeg, nbr_fc_w, nbr_fc_b, APg,
      align_b + 2, align_w + 4 * D_, attend_b + 2 * D_,
      wB + 2 * (size_t)RND_BLK2, gru_bih + 6 * D_, gru_bhh + 6 * D_,
      PgA, QgA, (float*)nullptr, (float*)nullptr);

  k_mol<<<dim3(B_), dim3(512), 0, stream>>>(
      hB, hOut, atom_mask, mol_align_w, mol_align_b, mol_attend_w, mol_attend_b,
      molT, molT + 128 * 384,
      mol_gru_bih, mol_gru_bhh, out_w, out_b, pred);
}

// Round 12
// 319.740 us; speedup vs baseline: 1.0393x; 1.0393x over previous
//
#include <hip/hip_runtime.h>
#include <cstddef>

// AttentiveFP forward. B=256 L=128 K=6 FA=39 FB=10 D=128 R=3 T=2. fp32 I/O.
// R12:
//  - k_round: reverted to R10's fused-GRU form (60us verified). R11's kd-split
//    REGRESSED (WRITE 32->48MB, 67us) -> k_round micro-surgery closed; the
//    R3/R10 form is the measured local optimum.
//  - k_mol: widened 512->1024 threads (4->16 waves/CU). Phase math lifted from
//    the R5/R6 mega-kernel's mol phase (numerically verified there): l/j work
//    split in eighths (ef=tid>>7), pg[7][6][132]+par8[8][132] combines. k_mol
//    was ~25 barrier-separated phases at 12.5% occupancy - pure exposed
//    latency; 16 waves/CU quadruples hiding. LDS ~97KB, 1 block/CU.
//  - k_prep (fused tr+pre), k_q0: unchanged from R10.

#define B_ 256
#define L_ 128
#define K_ 6
#define FA_ 39
#define FB_ 10
#define D_ 128
#define PAD_ 127
#define NEGC (-9.0e8f)
#define NA 32
#define NPAIR (NA * K_)   // 192

typedef unsigned short u16;
typedef unsigned int u32;
using s8 = __attribute__((ext_vector_type(8))) short;   // 8 x bf16
using f4 = __attribute__((ext_vector_type(4))) float;   // MFMA acc

#define WIH_H 0
#define WIH_L 49152
#define WHH_H 98304
#define WHH_L 147456
#define TW_H  196608
#define TW_L  212992
#define RND_BLK2 229376
#define NB16 (3 * RND_BLK2)
#define NMOLF (2 * 128 * 384)
#define PRE_BLKS 2048

__device__ __forceinline__ float lrelu(float x) { return x > 0.f ? x : 0.01f * x; }
__device__ __forceinline__ float eluf(float x)  { return x > 0.f ? x : expm1f(x); }
__device__ __forceinline__ float sigm(float x)  { return 1.f / (1.f + expf(-x)); }
__device__ __forceinline__ float b2f(u16 u) {
  union { u32 i; float f; } v; v.i = ((u32)u) << 16; return v.f;
}
__device__ __forceinline__ short f2b(float f) {  // RNE
  union { float f; u32 i; } v; v.f = f;
  u32 x = v.i;
  return (short)(u16)((x + 0x7FFFu + ((x >> 16) & 1u)) >> 16);
}

// Fused prep: blocks [0,PRE_BLKS) = per-atom precompute (h0/AP/P0);
// blocks [PRE_BLKS,..) = weight transform (frag-swizzled split bf16 + molT).
__global__ __launch_bounds__(256) void k_prep(
    // pre args
    const float* __restrict__ atom_list,
    const float* __restrict__ afc_w, const float* __restrict__ afc_b,
    const float* __restrict__ nbr_w,
    const float* __restrict__ aw0,
    u16* __restrict__ h0out, short* __restrict__ APg, float* __restrict__ PgA,
    // tr args
    const float* __restrict__ gwih, const float* __restrict__ gwhh,
    const float* __restrict__ attw,
    const float* __restrict__ mwih, const float* __restrict__ mwhh,
    short* __restrict__ wB, float* __restrict__ molT)
{
  int tid = threadIdx.x;
  if (blockIdx.x >= PRE_BLKS) {
    int idx = (blockIdx.x - PRE_BLKS) * 256 + tid;
    if (idx < NB16) {
      int r = idx / RND_BLK2, o = idx % RND_BLK2;
      float v; int lo;
      int e, kind;          // kind 0=wih, 1=whh, 2=tw
      if (o < 98304)      { kind = 0; lo = o / 49152; e = o % 49152; }
      else if (o < 196608){ kind = 1; int o2 = o - 98304; lo = o2 / 49152; e = o2 % 49152; }
      else                { kind = 2; int o2 = o - 196608; lo = o2 / 16384; e = o2 % 16384; }
      int gt = e >> 11, rem = e & 2047;
      int kc = rem >> 9, rem2 = rem & 511;
      int lane = rem2 >> 3, j = rem2 & 7;
      int col = lane & 15, quad = lane >> 4;
      int g = gt * 16 + col;
      int k = kc * 32 + quad * 8 + j;
      if (kind == 0)      v = gwih[(size_t)r * 49152 + g * 128 + k];
      else if (kind == 1) v = gwhh[(size_t)r * 49152 + g * 128 + k];
      else                v = attw[(size_t)r * 16384 + k * 128 + g];
      short hi = f2b(v);
      wB[idx] = lo ? f2b(v - b2f((u16)hi)) : hi;
    } else if (idx < NB16 + NMOLF) {
      int e2 = idx - NB16;
      int m = e2 / 49152, e = e2 % 49152, j = e / 384, g = e % 384;
      molT[e2] = (m ? mwhh : mwih)[g * 128 + j];
    }
    return;
  }

  // ---- pre branch (identical math to R3's k_pre; 256 thr, tid<128 active) ----
  int a0 = blockIdx.x * 16;
  __shared__ float xa[16 * 40];
  __shared__ float h0S[16][132];
  __shared__ float awS[128];
  __shared__ float partials[128];

  for (int i = tid; i < 16 * FA_; i += 256) {
    int a = i / FA_, c = i % FA_;
    xa[a * 40 + c] = atom_list[((size_t)(a0 + a)) * FA_ + c];
  }
  if (tid < 128) awS[tid] = aw0[tid];
  __syncthreads();

  if (tid < 128) {
    {
      float acc[16];
      float bv = afc_b[tid];
#pragma unroll
      for (int a = 0; a < 16; a++) acc[a] = bv;
#pragma unroll 2
      for (int j = 0; j < FA_; j++) {
        float w = afc_w[j * D_ + tid];
#pragma unroll
        for (int a = 0; a < 16; a++) acc[a] += xa[a * 40 + j] * w;
      }
#pragma unroll
      for (int a = 0; a < 16; a++) {
        float hv = lrelu(acc[a]);
        h0out[(size_t)(a0 + a) * D_ + tid] = (u16)f2b(hv);
        h0S[a][tid] = hv;
      }
    }
    {
      float acc[16];
#pragma unroll
      for (int a = 0; a < 16; a++) acc[a] = 0.f;
#pragma unroll 2
      for (int j = 0; j < FA_; j++) {
        float w = nbr_w[j * D_ + tid];
#pragma unroll
        for (int a = 0; a < 16; a++) acc[a] += xa[a * 40 + j] * w;
      }
#pragma unroll
      for (int a = 0; a < 16; a++)
        APg[(size_t)(a0 + a) * D_ + tid] = f2b(acc[a]);
    }
  }
  __syncthreads();
  if (tid < 128) {
    int a = tid >> 3, seg = tid & 7;
    float s = 0.f;
#pragma unroll
    for (int j = 0; j < 16; j++) s += h0S[a][seg * 16 + j] * awS[seg * 16 + j];
    partials[tid] = s;
  }
  __syncthreads();
  if (tid < 16) {
    float s = 0.f;
#pragma unroll
    for (int g = 0; g < 8; g++) s += partials[tid * 8 + g];
    PgA[a0 + tid] = s;
  }
}

// Per-pair Q0 = sum_d lrelu(AP[aidx]+bond[bidx]@Wb+nb) * awhi0.
__global__ __launch_bounds__(256) void k_q0(
    const float* __restrict__ bond_list,
    const float* __restrict__ nbr_w, const float* __restrict__ nbr_b,
    const float* __restrict__ aw0,
    const int* __restrict__ adeg, const int* __restrict__ bdeg,
    const short* __restrict__ APg, float* __restrict__ Q0g)
{
  int tid = threadIdx.x;
  __shared__ float WbS[10 * 128];
  __shared__ float nbS[128], ahS[128];
  for (int i = tid; i < 10 * 128; i += 256)
    WbS[i] = nbr_w[(FA_ + i / 128) * D_ + (i % 128)];
  if (tid < 128) { nbS[tid] = nbr_b[tid]; ahS[tid] = aw0[D_ + tid]; }
  __syncthreads();

  int p = blockIdx.x * 64 + (tid >> 2);
  int seg = tid & 3;
  int aidx = adeg[p], bidx = bdeg[p];
  int bb = p / (L_ * K_);
  const short* rowA = APg + ((size_t)bb * L_ + aidx) * D_;
  const float* brow = bond_list + ((size_t)bb * L_ + bidx) * FB_;
  float bnd[10];
#pragma unroll
  for (int m = 0; m < 10; m++) bnd[m] = brow[m];
  float s = 0.f;
  int j0 = seg * 32;
#pragma unroll 4
  for (int j = j0; j < j0 + 32; j++) {
    float v = b2f((u16)rowA[j]) + nbS[j];
#pragma unroll
    for (int m = 0; m < 10; m++) v += bnd[m] * WbS[m * 128 + j];
    s += lrelu(v) * ahS[j];
  }
  s += __shfl_xor(s, 1, 64);
  s += __shfl_xor(s, 2, 64);
  if (seg == 0) Q0g[p] = s;
}

template <int FIRST>
__global__ __launch_bounds__(512, 4) void k_round(
    const u16* __restrict__ hin,     // bf16 h
    u16* __restrict__ hout,          // bf16 h
    const float* __restrict__ bond_list,
    const int* __restrict__ adeg, const int* __restrict__ bdeg,
    const float* __restrict__ nbr_w, const float* __restrict__ nbr_b,
    const short* __restrict__ APg,
    const float* __restrict__ ab,
    const float* __restrict__ awN,
    const float* __restrict__ tb,
    const short* __restrict__ wR,
    const float* __restrict__ bih, const float* __restrict__ bhh,
    const float* __restrict__ Pr, const float* __restrict__ Qr,
    float* __restrict__ Pw, float* __restrict__ Qw)
{
  int tid  = threadIdx.x;
  int lane = tid & 63;
  int wv   = tid >> 6;         // wave 0..7
  int quad = lane >> 4;
  int col  = lane & 15;
  int aT   = tid >> 4;         // atom 0..31 (staging/ybar/copy mapping)
  int dg   = (tid & 15) * 8;   // dim-group base 0,8,..,120
  // XCD-bijective swizzle (grid=1024, 8 XCDs): the 4 tiles of each molecule
  // land on ONE XCD, and the mapping is launch-stable so round r+1 reads h
  // from the same L2 that round r wrote.
  int tile = (blockIdx.x & 7) * 128 + (blockIdx.x >> 3);
  int a0   = tile * NA;
  int bb   = a0 >> 7;

  const short* wihH = wR + WIH_H;
  const short* wihL = wR + WIH_L;
  const short* whhH = wR + WHH_H;
  const short* whhL = wR + WHH_L;
  const short* twH  = wR + TW_H;
  const short* twL  = wR + TW_L;

  __shared__ short hrowH[NA][136];                 // exact bf16 h (reused for hn out)
  __shared__ __align__(16) char arena[17408];      // ybar/ctx | hnrelu
  __shared__ float awNS[256];
  __shared__ float partials[512];
  __shared__ float pS[NA], qS[NPAIR], wkS[NPAIR], wsS[NA];
  __shared__ int aidxS[NPAIR];
  __shared__ int bidxS[FIRST ? NPAIR : 1];
  __shared__ float bwS[FIRST ? 1920 : 1];          // bond[192][10] only

  short* ybarH = (short*)arena;               // [32][136] (ctx reuses)
  short* ybarL = (short*)(arena + 8704);
  float* hnrel = (float*)arena;               // epilogue relu(hn) [32][132]

  if (tid < NPAIR) {
    int av = adeg[a0 * K_ + tid];
    aidxS[tid] = av;
    if (FIRST) { bidxS[tid] = bdeg[a0 * K_ + tid]; qS[tid] = Qr[a0 * K_ + tid]; }
    else       qS[tid] = Qr[bb * L_ + av];
  } else if (tid < NPAIR + NA) {
    pS[tid - NPAIR] = Pr[a0 + (tid - NPAIR)];
  }
  if (tid < 256) awNS[tid] = awN[tid];
  __syncthreads();

  // ---------- Phase 1: h tile (16B/thread) + FIRST bond staging + softmax ----------
  if (FIRST) {
    for (int i = tid; i < NPAIR * 10; i += 512) {
      int p = i / 10, m = i % 10;
      bwS[p * 10 + m] = bond_list[((size_t)bb * L_ + bidxS[p]) * FB_ + m];
    }
  }
  *(s8*)&hrowH[aT][dg] = *(const s8*)&hin[(size_t)(a0 + aT) * D_ + dg];

  // Softmax over K (first 32 lanes; fused into this barrier interval)
  if (tid < NA) {
    int a = tid;
    float abv = ab[0];
    float sc[K_];
    float m = -3.0e38f;
#pragma unroll
    for (int k = 0; k < K_; k++) {
      float s = lrelu(pS[a] + qS[a * K_ + k] + abv);
      if (aidxS[a * K_ + k] == PAD_) s += NEGC;
      sc[k] = s; m = fmaxf(m, s);
    }
    float es = 0.f;
#pragma unroll
    for (int k = 0; k < K_; k++) { sc[k] = expf(sc[k] - m); es += sc[k]; }
    float ws = 0.f;
#pragma unroll
    for (int k = 0; k < K_; k++) {
      float w = (aidxS[a * K_ + k] == PAD_) ? 0.f : sc[k] / es;
      wkS[a * K_ + k] = w; ws += w;
    }
    wsS[a] = ws;
  }
  __syncthreads();

  // ---------- ybar hi/lo: thread = (atom aT, dims dg..dg+7), 16B gathers ----------
  {
    float yb[8];
#pragma unroll
    for (int j = 0; j < 8; j++) yb[j] = 0.f;
    if (FIRST) {
#pragma unroll
      for (int h = 0; h < 2; h++) {
        float Wr[10][4];
#pragma unroll
        for (int m = 0; m < 10; m++) {
          float4 w = *(const float4*)&nbr_w[(FA_ + m) * D_ + dg + h * 4];
          Wr[m][0] = w.x; Wr[m][1] = w.y; Wr[m][2] = w.z; Wr[m][3] = w.w;
        }
        float4 nb4 = *(const float4*)&nbr_b[dg + h * 4];
        float nb[4] = {nb4.x, nb4.y, nb4.z, nb4.w};
#pragma unroll
        for (int k = 0; k < K_; k++) {
          int p = aT * K_ + k;
          ushort4 ap4 = *(const ushort4*)&APg[((size_t)bb * L_ + aidxS[p]) * D_ + dg + h * 4];
          float nf[4] = { b2f(ap4.x) + nb[0], b2f(ap4.y) + nb[1],
                          b2f(ap4.z) + nb[2], b2f(ap4.w) + nb[3] };
#pragma unroll
          for (int m = 0; m < 10; m++) {
            float bv = bwS[p * 10 + m];
#pragma unroll
            for (int j = 0; j < 4; j++) nf[j] += bv * Wr[m][j];
          }
          float w = wkS[p];
#pragma unroll
          for (int j = 0; j < 4; j++) yb[h * 4 + j] += w * lrelu(nf[j]);
        }
      }
    } else {
#pragma unroll
      for (int k = 0; k < K_; k++) {
        int p = aT * K_ + k;
        float w = wkS[p];
        s8 hv8 = *(const s8*)&hin[((size_t)bb * L_ + aidxS[p]) * D_ + dg];
#pragma unroll
        for (int j = 0; j < 8; j++) yb[j] += w * fmaxf(b2f((u16)hv8[j]), 0.f);
      }
    }
    s8 yh8, yl8;
#pragma unroll
    for (int j = 0; j < 8; j++) {
      short hi = f2b(yb[j]);
      yh8[j] = hi;
      yl8[j] = f2b(yb[j] - b2f((u16)hi));
    }
    *(s8*)&ybarH[aT * 136 + dg] = yh8;
    *(s8*)&ybarL[aT * 136 + dg] = yl8;
  }
  __syncthreads();

  // ---------- ctx = elu(ybar @ twT^T + wsum*tb), split MFMA (swizzled B) ----------
  {
    f4 c2[2] = {};
#pragma unroll
    for (int k0c = 0; k0c < 4; k0c++) {
      int fo = ((wv * 4 + k0c) * 64 + lane) * 8;
      s8 bwh = *(const s8*)&twH[fo];
      s8 bwl = *(const s8*)&twL[fo];
#pragma unroll
      for (int at = 0; at < 2; at++) {
        s8 ayh = *(const s8*)&ybarH[(at * 16 + col) * 136 + k0c * 32 + quad * 8];
        s8 ayl = *(const s8*)&ybarL[(at * 16 + col) * 136 + k0c * 32 + quad * 8];
        c2[at] = __builtin_amdgcn_mfma_f32_16x16x32_bf16(ayh, bwh, c2[at], 0, 0, 0);
        c2[at] = __builtin_amdgcn_mfma_f32_16x16x32_bf16(ayl, bwh, c2[at], 0, 0, 0);
        c2[at] = __builtin_amdgcn_mfma_f32_16x16x32_bf16(ayh, bwl, c2[at], 0, 0, 0);
      }
    }
    __syncthreads();
    int g = wv * 16 + col;
    float tbv = tb[g];
#pragma unroll
    for (int at = 0; at < 2; at++) {
#pragma unroll
      for (int r = 0; r < 4; r++) {
        int a = at * 16 + quad * 4 + r;
        float c = eluf(c2[at][r] + wsS[a] * tbv);
        short chs = f2b(c);
        ybarH[a * 136 + g] = chs;                    // ctxH
        ybarL[a * 136 + g] = f2b(c - b2f((u16)chs)); // ctxL
      }
    }
  }
  __syncthreads();

  // ---------- GRU via split MFMA (h exact bf16 -> 5 MFMA per (at,kd)) ----------
  {
    const short* ctxH = ybarH;
    const short* ctxL = ybarL;
    f4 gi[2][3] = {}, gh[2][3] = {};
#pragma unroll
    for (int k0c = 0; k0c < 4; k0c++) {
      s8 ach[2], acl[2], ahh[2];
#pragma unroll
      for (int at = 0; at < 2; at++) {
        ach[at] = *(const s8*)&ctxH[(at * 16 + col) * 136 + k0c * 32 + quad * 8];
        acl[at] = *(const s8*)&ctxL[(at * 16 + col) * 136 + k0c * 32 + quad * 8];
        ahh[at] = *(const s8*)&hrowH[at * 16 + col][k0c * 32 + quad * 8];
      }
#pragma unroll
      for (int kd = 0; kd < 3; kd++) {
        int gt = wv + kd * 8;
        int fo = ((gt * 4 + k0c) * 64 + lane) * 8;
        s8 bi_h = *(const s8*)&wihH[fo];
        s8 bi_l = *(const s8*)&wihL[fo];
        s8 bh_h = *(const s8*)&whhH[fo];
        s8 bh_l = *(const s8*)&whhL[fo];
#pragma unroll
        for (int at = 0; at < 2; at++) {
          gi[at][kd] = __builtin_amdgcn_mfma_f32_16x16x32_bf16(ach[at], bi_h, gi[at][kd], 0, 0, 0);
          gi[at][kd] = __builtin_amdgcn_mfma_f32_16x16x32_bf16(acl[at], bi_h, gi[at][kd], 0, 0, 0);
          gi[at][kd] = __builtin_amdgcn_mfma_f32_16x16x32_bf16(ach[at], bi_l, gi[at][kd], 0, 0, 0);
          gh[at][kd] = __builtin_amdgcn_mfma_f32_16x16x32_bf16(ahh[at], bh_h, gh[at][kd], 0, 0, 0);
          gh[at][kd] = __builtin_amdgcn_mfma_f32_16x16x32_bf16(ahh[at], bh_l, gh[at][kd], 0, 0, 0);
        }
      }
    }
    __syncthreads();

    {
      int ic = wv * 16 + col;
      float bi0 = bih[ic], bi1 = bih[D_ + ic], bi2 = bih[2 * D_ + ic];
      float bh0 = bhh[ic], bh1 = bhh[D_ + ic], bh2 = bhh[2 * D_ + ic];
#pragma unroll
      for (int at = 0; at < 2; at++) {
#pragma unroll
        for (int r = 0; r < 4; r++) {
          int a = at * 16 + quad * 4 + r;
          float rr = sigm(gi[at][0][r] + bi0 + gh[at][0][r] + bh0);
          float zz = sigm(gi[at][1][r] + bi1 + gh[at][1][r] + bh1);
          float nn = tanhf(gi[at][2][r] + bi2 + rr * (gh[at][2][r] + bh2));
          float hv = b2f((u16)hrowH[a][ic]);
          float hn = (1.f - zz) * nn + zz * hv;
          hrowH[a][ic] = f2b(hn);                    // stage bf16 hn in place
          if (Pw) hnrel[a * 132 + ic] = fmaxf(hn, 0.f);
        }
      }
    }
  }
  __syncthreads();

  // ---------- Coalesced hout copy (16B/thread, full 8KB tile) ----------
  *(s8*)&hout[(size_t)(a0 + aT) * D_ + dg] = *(const s8*)&hrowH[aT][dg];

  // ---------- Epilogue: P/Q for next round (skipped on last round) ----------
  if (Pw) {
    {
      int a = tid >> 4, dt = (tid >> 3) & 1, seg = tid & 7;
      float s = 0.f;
#pragma unroll
      for (int j = 0; j < 16; j++)
        s += hnrel[a * 132 + seg * 16 + j] * awNS[dt * 128 + seg * 16 + j];
      partials[tid] = s;
    }
    __syncthreads();
    if (tid < 64) {
      int a = tid >> 1, dt = tid & 1;
      float s = 0.f;
#pragma unroll
      for (int seg = 0; seg < 8; seg++) s += partials[a * 16 + dt * 8 + seg];
      if (dt) Qw[a0 + a] = s; else Pw[a0 + a] = s;
    }
  }
}

// --- block-wide reductions over 128 values (waves 0-1 hold data) ---
__device__ __forceinline__ float blk_sum128(float v, int tid, float* redS) {
  if (tid < 128) {
#pragma unroll
    for (int s = 1; s < 64; s <<= 1) v += __shfl_xor(v, s, 64);
    if ((tid & 63) == 0) redS[tid >> 6] = v;
  }
  __syncthreads();
  float r = redS[0] + redS[1];
  __syncthreads();
  return r;
}
__device__ __forceinline__ float blk_max128(float v, int tid, float* redS) {
  if (tid < 128) {
#pragma unroll
    for (int s = 1; s < 64; s <<= 1) v = fmaxf(v, __shfl_xor(v, s, 64));
    if ((tid & 63) == 0) redS[tid >> 6] = v;
  }
  __syncthreads();
  float r = fmaxf(redS[0], redS[1]);
  __syncthreads();
  return r;
}

// 1024-thread mol phase (lifted from the verified R5/R6 mega mol phase):
// eighth-splits (ef=tid>>7), pg[7][6][132]+par8[8][132] combines, 16 waves/CU.
__global__ __launch_bounds__(1024) void k_mol(
    const u16* __restrict__ hfin,    // bf16 final h
    float* __restrict__ hcopy,       // d_out h region (fp32)
    const float* __restrict__ amask,
    const float* __restrict__ maw, const float* __restrict__ mab,
    const float* __restrict__ mtw, const float* __restrict__ mtb,
    const float* __restrict__ wih_t, const float* __restrict__ whh_t,
    const float* __restrict__ bih, const float* __restrict__ bhh,
    const float* __restrict__ ow, const float* __restrict__ ob,
    float* __restrict__ pred)
{
  int b = blockIdx.x;
  int tid = threadIdx.x;
  int t128 = tid & 127;
  int ef = tid >> 7;           // eighth 0..7
  __shared__ float actS[L_][D_ + 1];   // 66048 B
  __shared__ float pg[7][6][132];      // 22176 B
  __shared__ float par8[8][132];       // 4224 B
  __shared__ float redS[2];
  __shared__ float wgt[128], ybv[132], ctxv[132], mfS[132], amol[132];
  __shared__ float msk[128], mawh[128], scf[128];

  if (tid < 128) { msk[tid] = amask[b * L_ + tid]; mawh[tid] = maw[D_ + tid]; }
  {
    int l = tid >> 3, c = (tid & 7) * 16;
#pragma unroll
    for (int hh = 0; hh < 2; hh++) {
      s8 h8 = *(const s8*)&hfin[(size_t)(b * L_ + l) * D_ + c + hh * 8];
      float hv[8];
#pragma unroll
      for (int j = 0; j < 8; j++) hv[j] = b2f((u16)h8[j]);
      float4 o0 = {hv[0], hv[1], hv[2], hv[3]};
      float4 o1 = {hv[4], hv[5], hv[6], hv[7]};
      *(float4*)&hcopy[((size_t)b * L_ + l) * D_ + c + hh * 8] = o0;
      *(float4*)&hcopy[((size_t)b * L_ + l) * D_ + c + hh * 8 + 4] = o1;
#pragma unroll
      for (int j = 0; j < 8; j++) actS[l][c + hh * 8 + j] = fmaxf(hv[j], 0.f);
    }
  }
  __syncthreads();

  // mol_feature (l-split eighths)
  {
    float s = 0.f;
#pragma unroll 2
    for (int i = 0; i < 16; i++) { int l = ef * 16 + i; s += actS[l][t128] * msk[l]; }
    par8[ef][t128] = s;
  }
  __syncthreads();
  if (ef == 0) {
    float mf = 0.f;
#pragma unroll
    for (int e = 0; e < 8; e++) mf += par8[e][t128];
    mfS[t128] = mf; amol[t128] = fmaxf(mf, 0.f);
  }
  __syncthreads();

  float mabv = mab[0];

  for (int t = 0; t < 2; t++) {
    // s0
    float s0 = blk_sum128((tid < 128) ? amol[tid] * maw[tid] : 0.f, tid, redS);

    // sc[l=t128] (j-split eighths)
    {
      float s = 0.f;
#pragma unroll 2
      for (int i = 0; i < 16; i++) { int j = ef * 16 + i; s += actS[t128][j] * mawh[j]; }
      par8[ef][t128] = s;
    }
    __syncthreads();
    if (ef == 0) {
      float sc = s0 + mabv;
#pragma unroll
      for (int e = 0; e < 8; e++) sc += par8[e][t128];
      sc = lrelu(sc);
      if (msk[t128] == 0.f) sc += NEGC;
      scf[t128] = sc;
    }
    __syncthreads();

    // softmax over l
    float scv = scf[t128];
    float mx = blk_max128((tid < 128) ? scv : -3.0e38f, tid, redS);
    float e = expf(scv - mx);
    float es = blk_sum128((tid < 128) ? e : 0.f, tid, redS);
    float w = (e / es) * msk[t128];
    if (tid < 128) wgt[t128] = w;
    float wsum = blk_sum128((tid < 128) ? w : 0.f, tid, redS);

    // y[j=t128] (l-split eighths)
    {
      float s = 0.f;
#pragma unroll 2
      for (int i = 0; i < 16; i++) { int l = ef * 16 + i; s += wgt[l] * actS[l][t128]; }
      par8[ef][t128] = s;
    }
    __syncthreads();
    if (ef == 0) {
      float y = 0.f;
#pragma unroll
      for (int e2 = 0; e2 < 8; e2++) y += par8[e2][t128];
      ybv[t128] = y;
    }
    __syncthreads();

    // ctx[g=t128] (j-split eighths)
    {
      float s = 0.f;
#pragma unroll 2
      for (int i = 0; i < 16; i++) { int j = ef * 16 + i; s += ybv[j] * mtw[j * D_ + t128]; }
      par8[ef][t128] = s;
    }
    __syncthreads();
    if (ef == 0) {
      float cx = wsum * mtb[t128];
#pragma unroll
      for (int e2 = 0; e2 < 8; e2++) cx += par8[e2][t128];
      ctxv[t128] = eluf(cx);
    }
    __syncthreads();

    // GRU (j-split eighths, x-stationary)
    {
      float gi0 = 0, gi1 = 0, gi2 = 0, gh0 = 0, gh1 = 0, gh2 = 0;
#pragma unroll 2
      for (int i = 0; i < 16; i++) {
        int j = ef * 16 + i;
        const float* wi = wih_t + (size_t)j * 384;
        const float* wh = whh_t + (size_t)j * 384;
        float xc = ctxv[j], xh = mfS[j];
        gi0 += xc * wi[t128]; gi1 += xc * wi[128 + t128]; gi2 += xc * wi[256 + t128];
        gh0 += xh * wh[t128]; gh1 += xh * wh[128 + t128]; gh2 += xh * wh[256 + t128];
      }
      if (ef > 0) {
        pg[ef - 1][0][t128] = gi0; pg[ef - 1][1][t128] = gi1; pg[ef - 1][2][t128] = gi2;
        pg[ef - 1][3][t128] = gh0; pg[ef - 1][4][t128] = gh1; pg[ef - 1][5][t128] = gh2;
      }
      __syncthreads();
      if (ef == 0) {
#pragma unroll
        for (int e2 = 0; e2 < 7; e2++) {
          gi0 += pg[e2][0][t128]; gi1 += pg[e2][1][t128]; gi2 += pg[e2][2][t128];
          gh0 += pg[e2][3][t128]; gh1 += pg[e2][4][t128]; gh2 += pg[e2][5][t128];
        }
        gi0 += bih[t128]; gi1 += bih[128 + t128]; gi2 += bih[256 + t128];
        gh0 += bhh[t128]; gh1 += bhh[128 + t128]; gh2 += bhh[256 + t128];
        float r = sigm(gi0 + gh0);
        float z = sigm(gi1 + gh1);
        float n = tanhf(gi2 + r * gh2);
        float hn = (1.f - z) * n + z * mfS[t128];
        mfS[t128] = hn;
        amol[t128] = fmaxf(hn, 0.f);
      }
      __syncthreads();
    }
  }

  float fin = blk_sum128((tid < 128) ? mfS[tid] * ow[tid] : 0.f, tid, redS);
  if (tid == 0) pred[b] = fin + ob[0];
}

extern "C" void kernel_launch(void* const* d_in, const int* in_sizes, int n_in,
                              void* d_out, int out_size, void* d_ws, size_t ws_size,
                              hipStream_t stream) {
  const float* atom_list    = (const float*)d_in[0];
  const float* bond_list    = (const float*)d_in[1];
  const float* atom_mask    = (const float*)d_in[2];
  const float* atom_fc_w    = (const float*)d_in[3];
  const float* atom_fc_b    = (const float*)d_in[4];
  const float* nbr_fc_w     = (const float*)d_in[5];
  const float* nbr_fc_b     = (const float*)d_in[6];
  const float* align_w      = (const float*)d_in[7];
  const float* align_b      = (const float*)d_in[8];
  const float* attend_w     = (const float*)d_in[9];
  const float* attend_b     = (const float*)d_in[10];
  const float* gru_wih      = (const float*)d_in[11];
  const float* gru_whh      = (const float*)d_in[12];
  const float* gru_bih      = (const float*)d_in[13];
  const float* gru_bhh      = (const float*)d_in[14];
  const float* mol_align_w  = (const float*)d_in[15];
  const float* mol_align_b  = (const float*)d_in[16];
  const float* mol_attend_w = (const float*)d_in[17];
  const float* mol_attend_b = (const float*)d_in[18];
  const float* mol_gru_wih  = (const float*)d_in[19];
  const float* mol_gru_whh  = (const float*)d_in[20];
  const float* mol_gru_bih  = (const float*)d_in[21];
  const float* mol_gru_bhh  = (const float*)d_in[22];
  const float* out_w        = (const float*)d_in[23];
  const float* out_b        = (const float*)d_in[24];
  const int*   adeg         = (const int*)d_in[25];
  const int*   bdeg         = (const int*)d_in[26];

  const size_t NH = (size_t)B_ * L_ * D_;
  u16*   hA   = (u16*)d_ws;              // NH shorts = 8.39 MB
  u16*   hB   = hA + NH;                 // NH shorts = 8.39 MB
  short* wB   = (short*)(hB + NH);       // NB16 shorts = 1.38 MB
  float* molT = (float*)(wB + NB16);     // NMOLF floats = 0.39 MB
  float* PgA  = molT + NMOLF;            // 4 x 128KB P/Q buffers
  float* QgA  = PgA + B_ * L_;
  float* PgB  = QgA + B_ * L_;
  float* QgB  = PgB + B_ * L_;
  short* APg  = (short*)(QgB + B_ * L_); // NH shorts = 8.39 MB
  float* Q0g  = (float*)(APg + NH);      // B*L*K floats = 0.79 MB
  float* hOut = (float*)d_out;
  float* pred = hOut + NH;

  // fused prep: 2048 pre-blocks + 3072 tr-blocks (concurrent)
  k_prep<<<dim3(PRE_BLKS + (NB16 + NMOLF) / 256), dim3(256), 0, stream>>>(
      atom_list, atom_fc_w, atom_fc_b, nbr_fc_w, align_w, hA, APg, PgA,
      gru_wih, gru_whh, attend_w, mol_gru_wih, mol_gru_whh, wB, molT);

  k_q0<<<dim3(B_ * L_ * K_ / 64), dim3(256), 0, stream>>>(
      bond_list, nbr_fc_w, nbr_fc_b, align_w, adeg, bdeg, APg, Q0g);

  dim3 blk(512), grd(B_ * L_ / NA);

  // r0: hA -> hB ; r1: hB -> hA ; r2: hA -> hB ; k_mol: hB -> d_out
  k_round<1><<<grd, blk, 0, stream>>>(
      hA, hB, bond_list, adeg, bdeg, nbr_fc_w, nbr_fc_b, APg,
      align_b, align_w + 2 * D_, attend_b,
      wB + 0 * (size_t)RND_BLK2, gru_bih, gru_bhh,
      PgA, Q0g, PgB, QgB);
  k_round<0><<<grd, blk, 0, stream>>>(
      hB, hA, bond_list, adeg, bdeg, nbr_fc_w, nbr_fc_b, APg,
      align_b + 1, align_w + 4 * D_, attend_b + D_,
      wB + 1 * (size_t)RND_BLK2, gru_bih + 3 * D_, gru_bhh + 3 * D_,
      PgB, QgB, PgA, QgA);
  k_round<0><<<grd, blk, 0, stream>>>(
      hA, hB, bond_list, adeg, bdeg, nbr_fc_w, nbr_fc_b, APg,
      align_b + 2, align_w + 4 * D_, attend_b + 2 * D_,
      wB + 2 * (size_t)RND_BLK2, gru_bih + 6 * D_, gru_bhh + 6 * D_,
      PgA, QgA, (float*)nullptr, (float*)nullptr);

  k_mol<<<dim3(B_), dim3(1024), 0, stream>>>(
      hB, hOut, atom_mask, mol_align_w, mol_align_b, mol_attend_w, mol_attend_b,
      molT, molT + 128 * 384,
      mol_gru_bih, mol_gru_bhh, out_w, out_b, pred);
}